// Round 11
// baseline (525.471 us; speedup 1.0000x reference)
//
#include <hip/hip_runtime.h>
#include <math.h>

typedef __attribute__((ext_vector_type(4))) float f32x4;
typedef __attribute__((ext_vector_type(8))) _Float16 f16x8;

__device__ __forceinline__ f32x4 mfma16h(f16x8 a, f16x8 b, f32x4 c){
  return __builtin_amdgcn_mfma_f32_16x16x32_f16(a, b, c, 0, 0, 0);
}
__device__ __forceinline__ void gload_lds16(const void* g, void* l){
  __builtin_amdgcn_global_load_lds((const __attribute__((address_space(1))) void*)g,
                                   (__attribute__((address_space(3))) void*)l, 16, 0, 0);
}

#define EXPC 0.1803368801111204f   // 0.125 * log2(e)
// global K swizzle phi(n) = bits (n3,n1,n0): chosen so phi(kappa(p)) = p&7 ->
// attn K-read XOR is (r16&7)*8, sequential across lanes = conflict-free (r10-verified).
#define PHI(n) (((((n)>>3)&1)<<2) | ((((n)>>1)&1)<<1) | ((n)&1))

// ---------------- weight stats: alpha=mean(w), beta-sum=sum|w| ----------------
__global__ __launch_bounds__(256) void k_wstats(const float* __restrict__ w1, const float* __restrict__ w2,
                                                double* __restrict__ dsum, double* __restrict__ dabs){
  const int mat = blockIdx.y;
  const float* wp = (mat < 6) ? (w1 + (size_t)mat*1048576) : (w2 + (size_t)(mat-6)*1048576);
  const f32x4* wv = (const f32x4*)wp + (size_t)blockIdx.x*8192;
  double s = 0.0, a = 0.0;
  for (int j = 0; j < 32; j++){
    f32x4 v = wv[j*256 + threadIdx.x];
    s += (double)v.x + (double)v.y + (double)v.z + (double)v.w;
    a += (double)fabsf(v.x) + (double)fabsf(v.y) + (double)fabsf(v.z) + (double)fabsf(v.w);
  }
  for (int d = 1; d < 64; d <<= 1){ s += __shfl_xor(s, d); a += __shfl_xor(a, d); }
  __shared__ double red[8];
  const int w = threadIdx.x >> 6;
  if ((threadIdx.x & 63) == 0){ red[w*2] = s; red[w*2+1] = a; }
  __syncthreads();
  if (threadIdx.x == 0){
    double S = red[0]+red[2]+red[4]+red[6], A = red[1]+red[3]+red[5]+red[7];
    atomicAdd(&dsum[mat], S);
    atomicAdd(&dabs[mat], A);
  }
}

// ---------------- binarize weights to fp16 {-1,0,+1}, swizzled GEMM-B layout ----------------
// layout: wb[mat][n][ (k&~63) + ((k&63) ^ 8*(n&7)) ]
__global__ __launch_bounds__(256) void k_binarize(const float* __restrict__ w1, const float* __restrict__ w2,
                                                  const double* __restrict__ dsum, _Float16* __restrict__ wb){
  const int blk = blockIdx.x;          // 6144 blocks, 512 per matrix
  const int mat = blk >> 9;
  const float alpha = (float)(dsum[mat] * (1.0/1048576.0));
  const float* wp = (mat < 6) ? (w1 + (size_t)mat*1048576) : (w2 + (size_t)(mat-6)*1048576);
  const size_t off = (size_t)(blk & 511)*2048 + (size_t)threadIdx.x*8;
  const int n = (int)(off >> 10), k = (int)(off & 1023);
  f32x4 v0 = *(const f32x4*)(wp + off), v1 = *(const f32x4*)(wp + off + 4);
  float vv[8] = {v0.x,v0.y,v0.z,v0.w,v1.x,v1.y,v1.z,v1.w};
  f16x8 pk;
  #pragma unroll
  for (int e = 0; e < 8; e++){
    float d = vv[e] - alpha;
    pk[e] = d > 0.f ? (_Float16)1.0f : (d < 0.f ? (_Float16)(-1.0f) : (_Float16)0.0f);
  }
  const size_t addr = (size_t)mat*1048576 + (size_t)n*1024 + (size_t)((k & ~63) + ((k & 63) ^ ((n&7)*8)));
  *(f16x8*)&wb[addr] = pk;
}

// ---------------- presplit (layer 0 only): x -> fp16 hi/lo K-layout + V^T-layout ----------------
// K:  Kh/Kl[bh][n][ d ^ 8*PHI(n&63) ]
// VT: Vh/Vl[bh][d][ t*64 + ((n&63) ^ 8*(d&7)) ]
__global__ __launch_bounds__(256) void k_presplit(const float* __restrict__ x,
                                                  _Float16* __restrict__ Kh, _Float16* __restrict__ Kl,
                                                  _Float16* __restrict__ Vh, _Float16* __restrict__ Vl){
  __shared__ _Float16 lh[64*72], ll[64*72];
  const int t = blockIdx.x, bh = blockIdx.y, b = bh>>4, h = bh&15;
  const int n = threadIdx.x>>2, c0 = (threadIdx.x&3)*16;
  const float* src = x + (size_t)b*1048576 + (size_t)(t*64+n)*1024 + h*64 + c0;
  const size_t kbase = ((size_t)bh*1024 + t*64 + n)*64;
  const int sw = PHI(n)*8;
  #pragma unroll
  for (int j = 0; j < 2; j++){
    f32x4 v0 = *(const f32x4*)(src + j*8);
    f32x4 v1 = *(const f32x4*)(src + j*8 + 4);
    float vv[8] = {v0.x,v0.y,v0.z,v0.w,v1.x,v1.y,v1.z,v1.w};
    f16x8 Hv, Lv;
    #pragma unroll
    for (int e = 0; e < 8; e++){
      _Float16 hh = (_Float16)vv[e];
      Hv[e] = hh; Lv[e] = (_Float16)(vv[e] - (float)hh);
      const int d = c0 + j*8 + e;
      lh[d*72 + n] = Hv[e]; ll[d*72 + n] = Lv[e];
    }
    const int db = c0 + j*8;
    *(f16x8*)&Kh[kbase + (db ^ sw)] = Hv;
    *(f16x8*)&Kl[kbase + (db ^ sw)] = Lv;
  }
  __syncthreads();
  const int d = threadIdx.x>>2, n0c = (threadIdx.x&3)*16;
  const size_t vbase = ((size_t)bh*64 + d)*1024 + t*64;
  const int sw2 = (d&7)*8;
  #pragma unroll
  for (int j = 0; j < 2; j++){
    const int nb = n0c + j*8;
    *(f16x8*)&Vh[vbase + (nb ^ sw2)] = *(const f16x8*)&lh[d*72 + nb];
    *(f16x8*)&Vl[vbase + (nb ^ sw2)] = *(const f16x8*)&ll[d*72 + nb];
  }
}

// ---------------- flash attention + residual: swapped QK^T, 2 q-sets per wave ----------------
// grid (32 bh, 8 qt), 256 thr, 1 block/CU. Each wave handles 32 q rows (two Q frag
// sets) so the per-tile K/V LDS frag reads (which don't depend on w and were 4x
// redundant across waves) are amortized over 2x the work -> LDS read BW per unit
// work halves (r10 model: LDS ~79% busy was the binding pipe).
// K rows staged at LDS position p holding actual key kappa(p)=[p5,p3,p2,p4,p1,p0]
// so the swapped-QK^T output lands directly on PV A-frag keys (in-lane P, r9).
__global__ __launch_bounds__(256, 1) void k_attn(const _Float16* __restrict__ Kh, const _Float16* __restrict__ Kl,
                                                 const _Float16* __restrict__ Vh, const _Float16* __restrict__ Vl,
                                                 const float* __restrict__ xin, float* __restrict__ xout){
  __shared__ _Float16 smb[32768];   // 64 KB: 2 x 32KB {Kh,Kl,Vh,Vl} dbuf; buf0 doubles as Q stage
  const int tid = threadIdx.x, w = tid>>6, l = tid&63, g = l>>4, r16 = l&15;
  const int bh = blockIdx.x, qt = blockIdx.y, b = bh>>4, h = bh&15;
  const _Float16* Kbh = Kh + (size_t)bh*65536;
  const _Float16* Kbl = Kl + (size_t)bh*65536;

  // staging offsets (t-invariant): LDS row p <- global key row kappa(p)
  size_t koffK[2], voff[2];
  int cbj[2];
  #pragma unroll
  for (int j = 0; j < 2; j++){
    const int cb = (j*4 + w)*64, c = cb + l;
    const int p  = c>>3;
    const int kp = (p&32) | ((p&12)<<1) | ((p&16)>>2) | (p&3);   // kappa(p)
    cbj[j]   = cb;
    koffK[j] = (size_t)kp*64 + (size_t)(l&7)*8;
    voff[j]  = ((size_t)bh*64 + (c>>3))*1024 + (size_t)(c&7)*8;
  }
  #define ASTAGE(buf, t) { _Float16* Bp = smb + (buf)*16384;                         \
    _Pragma("unroll")                                                                 \
    for (int j = 0; j < 2; j++){                                                      \
      gload_lds16(Kbh + (size_t)(t)*4096 + koffK[j], Bp + cbj[j]*8);                  \
      gload_lds16(Kbl + (size_t)(t)*4096 + koffK[j], Bp + 4096 + cbj[j]*8);           \
      gload_lds16(Vh + voff[j] + (t)*64, Bp + 8192 + cbj[j]*8);                       \
      gload_lds16(Vl + voff[j] + (t)*64, Bp + 12288 + cbj[j]*8);                      \
    } }

  // prologue: stage 128 Q rows (hi+lo, 32 KB) into buf0, read frags to regs, then tile 0
  const _Float16* Qsh = Kbh + (size_t)qt*8192;
  const _Float16* Qsl = Kbl + (size_t)qt*8192;
  _Float16* qs_h = smb;            // 8192 elements (16 KB)
  _Float16* qs_l = smb + 8192;
  #pragma unroll
  for (int j = 0; j < 4; j++){
    const int cb = (j*4 + w)*64;
    gload_lds16(Qsh + (size_t)(cb + l)*8, qs_h + cb*8);
    gload_lds16(Qsl + (size_t)(cb + l)*8, qs_l + cb*8);
  }
  __syncthreads();
  f16x8 aqh[2][2], aql[2][2];
  #pragma unroll
  for (int s2 = 0; s2 < 2; s2++){
    const int qrl = w*32 + s2*16 + r16;          // local q row 0..127
    const int phq8 = PHI(qrl & 63)*8;
    aqh[s2][0] = *(const f16x8*)&qs_h[qrl*64 + ((g*8) ^ phq8)];
    aqh[s2][1] = *(const f16x8*)&qs_h[qrl*64 + ((32 + g*8) ^ phq8)];
    aql[s2][0] = *(const f16x8*)&qs_l[qrl*64 + ((g*8) ^ phq8)];
    aql[s2][1] = *(const f16x8*)&qs_l[qrl*64 + ((32 + g*8) ^ phq8)];
  }
  __syncthreads();                 // all waves done reading Q before buf0 is overwritten
  ASTAGE(0, 0);
  __syncthreads();

  const int swk8 = (r16&7)*8;      // K-read XOR = phi(kappa(rk)) by construction
  float mI[2] = {-1e30f, -1e30f}, lI[2] = {0.f, 0.f};
  f32x4 acc[2][4];
  #pragma unroll
  for (int s2 = 0; s2 < 2; s2++)
    #pragma unroll
    for (int i = 0; i < 4; i++) acc[s2][i] = (f32x4){0.f,0.f,0.f,0.f};

  for (int t = 0; t < 16; t++){
    if (t < 15) ASTAGE((t+1)&1, t+1);          // prefetch next tile into other buffer
    const _Float16* kt_h = smb + (t&1)*16384;
    const _Float16* kt_l = kt_h + 4096;
    const _Float16* vt_h = kt_h + 8192;
    const _Float16* vt_l = kt_h + 12288;
    // swapped QK^T: A=K(staged rows), B=Q; K frags shared by both q-sets
    f32x4 s[2][4];
    #pragma unroll
    for (int c = 0; c < 4; c++){
      const int rk = c*16 + r16;
      const f16x8 kh0 = *(const f16x8*)&kt_h[rk*64 + ((g*8) ^ swk8)];
      const f16x8 kh1 = *(const f16x8*)&kt_h[rk*64 + ((32+g*8) ^ swk8)];
      const f16x8 kl0 = *(const f16x8*)&kt_l[rk*64 + ((g*8) ^ swk8)];
      const f16x8 kl1 = *(const f16x8*)&kt_l[rk*64 + ((32+g*8) ^ swk8)];
      #pragma unroll
      for (int s2 = 0; s2 < 2; s2++){
        f32x4 z = (f32x4){0.f,0.f,0.f,0.f};
        z = mfma16h(kh0, aqh[s2][0], z);
        z = mfma16h(kh1, aqh[s2][1], z);
        z = mfma16h(kh0, aql[s2][0], z);
        z = mfma16h(kh1, aql[s2][1], z);
        z = mfma16h(kl0, aqh[s2][0], z);
        z = mfma16h(kl1, aqh[s2][1], z);
        s[s2][c] = z;
      }
    }
    // per-lane scalar online softmax per set, exp2 domain, defer-rescale
    float rmax[2];
    #pragma unroll
    for (int s2 = 0; s2 < 2; s2++){
      float rm = s[s2][0][0];
      #pragma unroll
      for (int c = 0; c < 4; c++)
        #pragma unroll
        for (int i = 0; i < 4; i++) rm = fmaxf(rm, s[s2][c][i]);
      rm = fmaxf(rm, __shfl_xor(rm, 16));
      rm = fmaxf(rm, __shfl_xor(rm, 32));
      rmax[s2] = rm;
    }
    if (__any(fmaxf(rmax[0]-mI[0], rmax[1]-mI[1]) > 44.36f)){
      #pragma unroll
      for (int s2 = 0; s2 < 2; s2++){
        const float mn = fmaxf(mI[s2], rmax[s2]);
        const float fac = exp2f((mI[s2] - mn)*EXPC);
        lI[s2] *= fac;
        mI[s2] = mn;
        #pragma unroll
        for (int i = 0; i < 4; i++){
          const float fi = __shfl(fac, g*4 + i);
          #pragma unroll
          for (int dc = 0; dc < 4; dc++) acc[s2][dc][i] *= fi;
        }
      }
    }
    f16x8 aph[2][2], apl[2][2];
    #pragma unroll
    for (int s2 = 0; s2 < 2; s2++){
      const float mC = mI[s2]*EXPC;
      float rsum = 0.f;
      #pragma unroll
      for (int c = 0; c < 4; c++)
        #pragma unroll
        for (int i = 0; i < 4; i++){
          const float p = exp2f(fmaf(s[s2][c][i], EXPC, -mC));
          const _Float16 ph = (_Float16)p;
          aph[s2][c>>1][(c&1)*4 + i] = ph;
          apl[s2][c>>1][(c&1)*4 + i] = (_Float16)(p - (float)ph);
          rsum += p;
        }
      rsum += __shfl_xor(rsum, 16);
      rsum += __shfl_xor(rsum, 32);
      lI[s2] += rsum;
    }
    // PV: A = in-lane P (keys ks*32+g*8..+7 by construction); V frags shared by sets
    #pragma unroll
    for (int ks = 0; ks < 2; ks++){
      #pragma unroll
      for (int dc = 0; dc < 4; dc++){
        const int vr = dc*16 + r16;
        const f16x8 bvh = *(const f16x8*)&vt_h[vr*64 + ((ks*32 + g*8) ^ swk8)];
        const f16x8 bvl = *(const f16x8*)&vt_l[vr*64 + ((ks*32 + g*8) ^ swk8)];
        #pragma unroll
        for (int s2 = 0; s2 < 2; s2++){
          acc[s2][dc] = mfma16h(aph[s2][ks], bvh, acc[s2][dc]);
          acc[s2][dc] = mfma16h(apl[s2][ks], bvh, acc[s2][dc]);
          acc[s2][dc] = mfma16h(aph[s2][ks], bvl, acc[s2][dc]);
        }
      }
    }
    __syncthreads();   // drains vmcnt: next buffer staged; all waves done with buf t&1
  }
  #undef ASTAGE
  #pragma unroll
  for (int s2 = 0; s2 < 2; s2++)
    #pragma unroll
    for (int i = 0; i < 4; i++){
      const float li = __shfl(lI[s2], g*4 + i);
      const float inv = 1.f/li;
      const int row = qt*128 + w*32 + s2*16 + g*4 + i;
      #pragma unroll
      for (int dc = 0; dc < 4; dc++){
        const size_t idx = (size_t)b*1048576 + (size_t)row*1024 + h*64 + dc*16 + r16;
        xout[idx] = acc[s2][dc][i]*inv + xin[idx];
      }
    }
}

// ---------------- layernorm; SPLIT=1 writes fp16 hi/lo in swizzled A-layout ----------------
template<int SPLIT>
__global__ __launch_bounds__(256) void k_ln(const float* __restrict__ x, const float* __restrict__ gg,
                                            const float* __restrict__ bb, float* __restrict__ outf,
                                            _Float16* __restrict__ Oh, _Float16* __restrict__ Ol){
  const int row = blockIdx.x*4 + (threadIdx.x>>6);
  const int lane = threadIdx.x & 63;
  const float* xr = x + (size_t)row*1024;
  f32x4 v[4];
  float s = 0.f, q = 0.f;
  #pragma unroll
  for (int c = 0; c < 2; c++){
    v[c*2]   = *(const f32x4*)(xr + c*512 + lane*8);
    v[c*2+1] = *(const f32x4*)(xr + c*512 + lane*8 + 4);
    #pragma unroll
    for (int e = 0; e < 4; e++){
      s += v[c*2][e] + v[c*2+1][e];
      q += v[c*2][e]*v[c*2][e] + v[c*2+1][e]*v[c*2+1][e];
    }
  }
  for (int d = 1; d < 64; d <<= 1){ s += __shfl_xor(s,d); q += __shfl_xor(q,d); }
  const float mean = s * (1.f/1024.f);
  const float var  = q * (1.f/1024.f) - mean*mean;
  const float rstd = rsqrtf(var + 1e-5f);
  #pragma unroll
  for (int c = 0; c < 2; c++){
    const int col = c*512 + lane*8;
    f32x4 g0 = *(const f32x4*)(gg + col), g1 = *(const f32x4*)(gg + col + 4);
    f32x4 b0 = *(const f32x4*)(bb + col), b1 = *(const f32x4*)(bb + col + 4);
    float h[8];
    #pragma unroll
    for (int e = 0; e < 4; e++){
      h[e]   = (v[c*2][e]  -mean)*rstd*g0[e] + b0[e];
      h[e+4] = (v[c*2+1][e]-mean)*rstd*g1[e] + b1[e];
    }
    if (SPLIT){
      f16x8 Hv, Lv;
      #pragma unroll
      for (int e = 0; e < 8; e++){
        _Float16 hh = (_Float16)h[e];
        Hv[e] = hh; Lv[e] = (_Float16)(h[e] - (float)hh);
      }
      const size_t addr = (size_t)row*1024 + c*512 + (lane>>3)*64 + (((lane&7)*8) ^ ((row&7)*8));
      *(f16x8*)&Oh[addr] = Hv;
      *(f16x8*)&Ol[addr] = Lv;
    } else {
      f32x4 o0, o1;
      #pragma unroll
      for (int e = 0; e < 4; e++){ o0[e] = h[e]; o1[e] = h[e+4]; }
      *(f32x4*)(outf + (size_t)row*1024 + col) = o0;
      *(f32x4*)(outf + (size_t)row*1024 + col + 4) = o1;
    }
  }
}

// ---------------- bitlinear GEMM: C[2048,1024] = (Ah+Al).Wb^T * beta ----------------
// BM=BN=64, BK=64, 4 waves (2Mx2N, wave-tile 32x32), double-buffered gload staging.
// MODE 0: GELU -> split fp16 out (swizzled A-layout).
// MODE 1: += into fp32 residual; if Kh!=null, ALSO produce next layer's K/V split
//         layouts (fused presplit: this block == presplit unit t=by&15, bh=(by>>4)*16+bx).
template<int MODE>
__global__ __launch_bounds__(256) void k_gemm(const _Float16* __restrict__ Ah, const _Float16* __restrict__ Al,
                                              const _Float16* __restrict__ Wg,
                                              float* __restrict__ out32,
                                              _Float16* __restrict__ Oh, _Float16* __restrict__ Ol,
                                              const double* __restrict__ dabs_slot,
                                              _Float16* __restrict__ Kh, _Float16* __restrict__ Kl,
                                              _Float16* __restrict__ Vh, _Float16* __restrict__ Vl){
  __shared__ _Float16 smb[24576];   // 2 x (A-hi 4096 + A-lo 4096 + B 4096); reused post-loop
  const int tid = threadIdx.x, w = tid>>6, l = tid&63, g = l>>4, r16 = l&15;
  const int wm = w>>1, wn = w&1;
  const int n0 = blockIdx.x*64, m0 = blockIdx.y*64;
  const float scale = (float)(*dabs_slot * (1.0/1048576.0));
  const int swr = (r16&7)*8;
  f32x4 acc[2][2] = {};
  #define STAGE(buf, k0) { _Float16* Bp = smb + (buf)*12288;                              \
    _Pragma("unroll")                                                                     \
    for (int j = 0; j < 2; j++){                                                          \
      const int cb = (j*4 + w)*64; const int c = cb + l;                                  \
      const int r = c>>3; const int cc = (c&7)*8;                                         \
      gload_lds16(Ah + (size_t)(m0 + r)*1024 + (k0) + cc, Bp + cb*8);                     \
      gload_lds16(Al + (size_t)(m0 + r)*1024 + (k0) + cc, Bp + 4096 + cb*8);              \
      gload_lds16(Wg + (size_t)(n0 + r)*1024 + (k0) + cc, Bp + 8192 + cb*8);              \
    } }
  STAGE(0, 0);
  __syncthreads();
  for (int t = 0; t < 16; t++){
    if (t < 15) STAGE((t+1)&1, (t+1)*64);
    const _Float16* Bp = smb + (t&1)*12288;
    #pragma unroll
    for (int kk = 0; kk < 2; kk++){
      f16x8 ah[2], al[2], bf[2];
      const int col = (kk*32 + g*8) ^ swr;
      #pragma unroll
      for (int mi = 0; mi < 2; mi++){
        const int row = wm*32 + mi*16 + r16;
        ah[mi] = *(const f16x8*)&Bp[row*64 + col];
        al[mi] = *(const f16x8*)&Bp[4096 + row*64 + col];
      }
      #pragma unroll
      for (int ni = 0; ni < 2; ni++){
        const int row = wn*32 + ni*16 + r16;
        bf[ni] = *(const f16x8*)&Bp[8192 + row*64 + col];
      }
      #pragma unroll
      for (int mi = 0; mi < 2; mi++)
        #pragma unroll
        for (int ni = 0; ni < 2; ni++){
          acc[mi][ni] = mfma16h(ah[mi], bf[ni], acc[mi][ni]);
          acc[mi][ni] = mfma16h(al[mi], bf[ni], acc[mi][ni]);
        }
    }
    __syncthreads();
  }
  #undef STAGE
  // post-loop LDS reuse (all waves past final barrier): split-tile staging for fused KV
  _Float16* kh_t = smb;            // [64][72] token-major hi
  _Float16* kl_t = smb + 4608;     // [64][72] token-major lo
  _Float16* lhv  = smb + 9216;     // [64][72] d-major hi
  _Float16* llv  = smb + 13824;    // [64][72] d-major lo
  #pragma unroll
  for (int mi = 0; mi < 2; mi++)
    #pragma unroll
    for (int ni = 0; ni < 2; ni++)
      #pragma unroll
      for (int i = 0; i < 4; i++){
        const int rr = m0 + wm*32 + mi*16 + g*4 + i;
        const int cc = n0 + wn*32 + ni*16 + r16;
        float vv = acc[mi][ni][i] * scale;
        if (MODE == 0){
          vv = 0.5f*vv*(1.f + erff(vv*0.70710678118f));
          _Float16 hh = (_Float16)vv;
          const size_t addr = (size_t)rr*1024 + (cc & ~63) + ((cc & 63) ^ ((rr&7)*8));
          Oh[addr] = hh;
          Ol[addr] = (_Float16)(vv - (float)hh);
        } else {
          const size_t idx = (size_t)rr*1024 + cc;
          const float xnew = out32[idx] + vv;
          out32[idx] = xnew;
          if (Kh){
            const int nl = wm*32 + mi*16 + g*4 + i;   // token within tile
            const int dl = wn*32 + ni*16 + r16;       // d within head
            const _Float16 hh = (_Float16)xnew;
            const _Float16 lo = (_Float16)(xnew - (float)hh);
            kh_t[nl*72 + dl] = hh;  kl_t[nl*72 + dl] = lo;
            lhv [dl*72 + nl] = hh;  llv [dl*72 + nl] = lo;
          }
        }
      }
  if (MODE == 1 && Kh){
    __syncthreads();
    const int n = tid>>2, c0q = (tid&3)*16;
    const int bh = (blockIdx.y>>4)*16 + blockIdx.x;
    const int tseq = blockIdx.y & 15;
    const size_t kbase = ((size_t)bh*1024 + tseq*64 + n)*64;
    const int swn = PHI(n)*8;
    const size_t vbase = ((size_t)bh*64 + n)*1024 + tseq*64;
    const int sw2 = (n&7)*8;
    #pragma unroll
    for (int j = 0; j < 2; j++){
      const int db = c0q + j*8;
      *(f16x8*)&Kh[kbase + (db ^ swn)] = *(const f16x8*)&kh_t[n*72 + db];
      *(f16x8*)&Kl[kbase + (db ^ swn)] = *(const f16x8*)&kl_t[n*72 + db];
      *(f16x8*)&Vh[vbase + (db ^ sw2)] = *(const f16x8*)&lhv[n*72 + db];
      *(f16x8*)&Vl[vbase + (db ^ sw2)] = *(const f16x8*)&llv[n*72 + db];
    }
  }
}

extern "C" void kernel_launch(void* const* d_in, const int* in_sizes, int n_in,
                              void* d_out, int out_size, void* d_ws, size_t ws_size,
                              hipStream_t stream){
  const float* x_in = (const float*)d_in[0];
  const float* ln_g = (const float*)d_in[1];
  const float* ln_b = (const float*)d_in[2];
  const float* w1   = (const float*)d_in[3];
  const float* w2   = (const float*)d_in[4];
  const float* fg   = (const float*)d_in[5];
  const float* fb   = (const float*)d_in[6];

  char* ws = (char*)d_ws;
  double*   dsum  = (double*)ws;            // 12
  double*   dabs  = (double*)(ws + 96);     // 12
  _Float16* wb = (_Float16*)(ws + 256);     // 12 * 1M fp16 = 24 MB
  size_t o = 256 + 12ull*1048576ull*2ull;
  float* xA = (float*)(ws + o); o += 2048ull*1024*4;
  float* xB = (float*)(ws + o); o += 2048ull*1024*4;
  _Float16* Kh = (_Float16*)(ws + o); o += 2048ull*1024*2;
  _Float16* Kl = (_Float16*)(ws + o); o += 2048ull*1024*2;
  _Float16* Vh = (_Float16*)(ws + o); o += 2048ull*1024*2;
  _Float16* Vl = (_Float16*)(ws + o); o += 2048ull*1024*2;
  _Float16* Ahb = (_Float16*)(ws + o); o += 2048ull*1024*2;
  _Float16* Alb = (_Float16*)(ws + o); o += 2048ull*1024*2;
  _Float16* Ghb = (_Float16*)(ws + o); o += 2048ull*1024*2;
  _Float16* Glb = (_Float16*)(ws + o); o += 2048ull*1024*2;

  hipMemsetAsync(ws, 0, 256, stream);
  k_wstats  <<<dim3(32,12), 256, 0, stream>>>(w1, w2, dsum, dabs);
  k_binarize<<<6144,        256, 0, stream>>>(w1, w2, dsum, wb);
  k_presplit<<<dim3(16,32), 256, 0, stream>>>(x_in, Kh, Kl, Vh, Vl);

  const float* xc = x_in;
  for (int i = 0; i < 6; i++){
    float* xn = (i & 1) ? xB : xA;
    const bool last = (i == 5);
    k_attn    <<<dim3(32,8), 256, 0, stream>>>(Kh, Kl, Vh, Vl, xc, xn);
    k_ln<1>   <<<512, 256, 0, stream>>>(xn, ln_g + (size_t)i*1024, ln_b + (size_t)i*1024,
                                        nullptr, Ahb, Alb);
    k_gemm<0> <<<dim3(16,32), 256, 0, stream>>>(Ahb, Alb, wb + (size_t)i*1048576,
                                                nullptr, Ghb, Glb, &dabs[i],
                                                nullptr, nullptr, nullptr, nullptr);
    k_gemm<1> <<<dim3(16,32), 256, 0, stream>>>(Ghb, Glb, wb + (size_t)(6+i)*1048576,
                                                xn, nullptr, nullptr, &dabs[6+i],
                                                last ? nullptr : Kh, last ? nullptr : Kl,
                                                last ? nullptr : Vh, last ? nullptr : Vl);
    xc = xn;
  }
  k_ln<0><<<512, 256, 0, stream>>>(xc, fg, fb, (float*)d_out, nullptr, nullptr);
}

// Round 12
// 509.488 us; speedup vs baseline: 1.0314x; 1.0314x over previous
//
#include <hip/hip_runtime.h>
#include <math.h>

typedef __attribute__((ext_vector_type(4))) float f32x4;
typedef __attribute__((ext_vector_type(8))) _Float16 f16x8;

__device__ __forceinline__ f32x4 mfma16h(f16x8 a, f16x8 b, f32x4 c){
  return __builtin_amdgcn_mfma_f32_16x16x32_f16(a, b, c, 0, 0, 0);
}
__device__ __forceinline__ void gload_lds16(const void* g, void* l){
  __builtin_amdgcn_global_load_lds((const __attribute__((address_space(1))) void*)g,
                                   (__attribute__((address_space(3))) void*)l, 16, 0, 0);
}

#define EXPC 0.1803368801111204f   // 0.125 * log2(e)
// global K swizzle phi(n) = bits (n3,n1,n0): chosen so phi(kappa(p)) = p&7 ->
// attn K-read XOR is (r16&7)*8, sequential across lanes = conflict-free (r10-verified).
#define PHI(n) (((((n)>>3)&1)<<2) | ((((n)>>1)&1)<<1) | ((n)&1))

// ---------------- weight stats: alpha=mean(w), beta-sum=sum|w| ----------------
__global__ __launch_bounds__(256) void k_wstats(const float* __restrict__ w1, const float* __restrict__ w2,
                                                double* __restrict__ dsum, double* __restrict__ dabs){
  const int mat = blockIdx.y;
  const float* wp = (mat < 6) ? (w1 + (size_t)mat*1048576) : (w2 + (size_t)(mat-6)*1048576);
  const f32x4* wv = (const f32x4*)wp + (size_t)blockIdx.x*8192;
  double s = 0.0, a = 0.0;
  for (int j = 0; j < 32; j++){
    f32x4 v = wv[j*256 + threadIdx.x];
    s += (double)v.x + (double)v.y + (double)v.z + (double)v.w;
    a += (double)fabsf(v.x) + (double)fabsf(v.y) + (double)fabsf(v.z) + (double)fabsf(v.w);
  }
  for (int d = 1; d < 64; d <<= 1){ s += __shfl_xor(s, d); a += __shfl_xor(a, d); }
  __shared__ double red[8];
  const int w = threadIdx.x >> 6;
  if ((threadIdx.x & 63) == 0){ red[w*2] = s; red[w*2+1] = a; }
  __syncthreads();
  if (threadIdx.x == 0){
    double S = red[0]+red[2]+red[4]+red[6], A = red[1]+red[3]+red[5]+red[7];
    atomicAdd(&dsum[mat], S);
    atomicAdd(&dabs[mat], A);
  }
}

// ---------------- binarize weights to fp16 {-1,0,+1}, swizzled GEMM-B layout ----------------
// layout: wb[mat][n][ (k&~63) + ((k&63) ^ 8*(n&7)) ]
__global__ __launch_bounds__(256) void k_binarize(const float* __restrict__ w1, const float* __restrict__ w2,
                                                  const double* __restrict__ dsum, _Float16* __restrict__ wb){
  const int blk = blockIdx.x;          // 6144 blocks, 512 per matrix
  const int mat = blk >> 9;
  const float alpha = (float)(dsum[mat] * (1.0/1048576.0));
  const float* wp = (mat < 6) ? (w1 + (size_t)mat*1048576) : (w2 + (size_t)(mat-6)*1048576);
  const size_t off = (size_t)(blk & 511)*2048 + (size_t)threadIdx.x*8;
  const int n = (int)(off >> 10), k = (int)(off & 1023);
  f32x4 v0 = *(const f32x4*)(wp + off), v1 = *(const f32x4*)(wp + off + 4);
  float vv[8] = {v0.x,v0.y,v0.z,v0.w,v1.x,v1.y,v1.z,v1.w};
  f16x8 pk;
  #pragma unroll
  for (int e = 0; e < 8; e++){
    float d = vv[e] - alpha;
    pk[e] = d > 0.f ? (_Float16)1.0f : (d < 0.f ? (_Float16)(-1.0f) : (_Float16)0.0f);
  }
  const size_t addr = (size_t)mat*1048576 + (size_t)n*1024 + (size_t)((k & ~63) + ((k & 63) ^ ((n&7)*8)));
  *(f16x8*)&wb[addr] = pk;
}

// ---------------- presplit (layer 0 only): x -> fp16 hi/lo K-layout + V^T-layout ----------------
// K:  Kh/Kl[bh][n][ d ^ 8*PHI(n&63) ]
// VT: Vh/Vl[bh][d][ t*64 + ((n&63) ^ 8*(d&7)) ]
__global__ __launch_bounds__(256) void k_presplit(const float* __restrict__ x,
                                                  _Float16* __restrict__ Kh, _Float16* __restrict__ Kl,
                                                  _Float16* __restrict__ Vh, _Float16* __restrict__ Vl){
  __shared__ _Float16 lh[64*72], ll[64*72];
  const int t = blockIdx.x, bh = blockIdx.y, b = bh>>4, h = bh&15;
  const int n = threadIdx.x>>2, c0 = (threadIdx.x&3)*16;
  const float* src = x + (size_t)b*1048576 + (size_t)(t*64+n)*1024 + h*64 + c0;
  const size_t kbase = ((size_t)bh*1024 + t*64 + n)*64;
  const int sw = PHI(n)*8;
  #pragma unroll
  for (int j = 0; j < 2; j++){
    f32x4 v0 = *(const f32x4*)(src + j*8);
    f32x4 v1 = *(const f32x4*)(src + j*8 + 4);
    float vv[8] = {v0.x,v0.y,v0.z,v0.w,v1.x,v1.y,v1.z,v1.w};
    f16x8 Hv, Lv;
    #pragma unroll
    for (int e = 0; e < 8; e++){
      _Float16 hh = (_Float16)vv[e];
      Hv[e] = hh; Lv[e] = (_Float16)(vv[e] - (float)hh);
      const int d = c0 + j*8 + e;
      lh[d*72 + n] = Hv[e]; ll[d*72 + n] = Lv[e];
    }
    const int db = c0 + j*8;
    *(f16x8*)&Kh[kbase + (db ^ sw)] = Hv;
    *(f16x8*)&Kl[kbase + (db ^ sw)] = Lv;
  }
  __syncthreads();
  const int d = threadIdx.x>>2, n0c = (threadIdx.x&3)*16;
  const size_t vbase = ((size_t)bh*64 + d)*1024 + t*64;
  const int sw2 = (d&7)*8;
  #pragma unroll
  for (int j = 0; j < 2; j++){
    const int nb = n0c + j*8;
    *(f16x8*)&Vh[vbase + (nb ^ sw2)] = *(const f16x8*)&lh[d*72 + nb];
    *(f16x8*)&Vl[vbase + (nb ^ sw2)] = *(const f16x8*)&ll[d*72 + nb];
  }
}

// ---------------- flash attention + residual: swapped QK^T, T15 S-pipeline ----------------
// grid (32 bh, 16 qt), 256 thr, 2 blocks/CU. Per iteration: QK(t+1) [MFMA, indep]
// is issued BEFORE softmax(t) [VALU] so the two pipes overlap; PV(t) follows.
// K staged 2 tiles ahead (3 K-bufs), V 1 ahead (2 V-bufs) = 80KB. Q frags load
// directly from global (one-time). In-lane P via kappa-permuted K staging (r9/r10).
__global__ __launch_bounds__(256) void k_attn(const _Float16* __restrict__ Kh, const _Float16* __restrict__ Kl,
                                              const _Float16* __restrict__ Vh, const _Float16* __restrict__ Vl,
                                              const float* __restrict__ xin, float* __restrict__ xout){
  __shared__ _Float16 smb[40960];   // 80 KB: K0,K1,K2 (8192 el each) + V0,V1 (8192 el each)
  const int tid = threadIdx.x, w = tid>>6, l = tid&63, g = l>>4, r16 = l&15;
  const int bh = blockIdx.x, qt = blockIdx.y, b = bh>>4, h = bh&15;
  const _Float16* Kbh = Kh + (size_t)bh*65536;
  const _Float16* Kbl = Kl + (size_t)bh*65536;

  // staging offsets (t-invariant): K LDS row p <- global key row kappa(p)
  size_t koffK[2], voff[2];
  int cbj[2];
  #pragma unroll
  for (int j = 0; j < 2; j++){
    const int cb = (j*4 + w)*64, c = cb + l;
    const int p  = c>>3;
    const int kp = (p&32) | ((p&12)<<1) | ((p&16)>>2) | (p&3);   // kappa(p)
    cbj[j]   = cb;
    koffK[j] = (size_t)kp*64 + (size_t)(l&7)*8;
    voff[j]  = ((size_t)bh*64 + (c>>3))*1024 + (size_t)(c&7)*8;
  }
  #define KSTAGE(PK, T) { _Pragma("unroll")                                          \
    for (int j = 0; j < 2; j++){                                                      \
      gload_lds16(Kbh + (size_t)(T)*4096 + koffK[j], (PK) + cbj[j]*8);                \
      gload_lds16(Kbl + (size_t)(T)*4096 + koffK[j], (PK) + 4096 + cbj[j]*8);         \
    } }
  #define VSTAGE(PV, T) { _Pragma("unroll")                                          \
    for (int j = 0; j < 2; j++){                                                      \
      gload_lds16(Vh + voff[j] + (T)*64, (PV) + cbj[j]*8);                            \
      gload_lds16(Vl + voff[j] + (T)*64, (PV) + 4096 + cbj[j]*8);                     \
    } }

  _Float16* pKo = smb;            // K buf holding tile t (dead after QK(t))
  _Float16* pKn = smb + 8192;     // K buf holding tile t+1
  _Float16* pKs = smb + 16384;    // K stage target (tile t+2)
  _Float16* pVc = smb + 24576;    // V buf holding tile t
  _Float16* pVs = smb + 32768;    // V stage target (tile t+1)

  // prologue: stage K0,K1,V0; Q frags straight from global (one-time, L2)
  KSTAGE(pKo, 0); KSTAGE(pKn, 1); VSTAGE(pVc, 0);
  const int qrow = w*16 + r16;
  const int phq8 = PHI(qrow)*8;
  const size_t qb = (size_t)qt*4096 + (size_t)qrow*64;
  const f16x8 aqh0 = *(const f16x8*)&Kbh[qb + ((g*8) ^ phq8)];
  const f16x8 aqh1 = *(const f16x8*)&Kbh[qb + ((32 + g*8) ^ phq8)];
  const f16x8 aql0 = *(const f16x8*)&Kbl[qb + ((g*8) ^ phq8)];
  const f16x8 aql1 = *(const f16x8*)&Kbl[qb + ((32 + g*8) ^ phq8)];
  __syncthreads();

  const int swk8 = (r16&7)*8;      // K/V-read XOR (conflict-free by PHI construction)
  float mI = -1e30f, lI = 0.f;
  f32x4 acc[4], sA[4], sB[4];
  #pragma unroll
  for (int i = 0; i < 4; i++) acc[i] = (f32x4){0.f,0.f,0.f,0.f};

  #define QKT(PK, SD) { const _Float16* kt_h = (PK); const _Float16* kt_l = (PK) + 4096;  \
    _Pragma("unroll")                                                                      \
    for (int c = 0; c < 4; c++){                                                           \
      const int rk = c*16 + r16;                                                           \
      const f16x8 kh0 = *(const f16x8*)&kt_h[rk*64 + ((g*8) ^ swk8)];                      \
      const f16x8 kh1 = *(const f16x8*)&kt_h[rk*64 + ((32+g*8) ^ swk8)];                   \
      const f16x8 kl0 = *(const f16x8*)&kt_l[rk*64 + ((g*8) ^ swk8)];                      \
      const f16x8 kl1 = *(const f16x8*)&kt_l[rk*64 + ((32+g*8) ^ swk8)];                   \
      f32x4 z = (f32x4){0.f,0.f,0.f,0.f};                                                  \
      z = mfma16h(kh0, aqh0, z);                                                           \
      z = mfma16h(kh1, aqh1, z);                                                           \
      z = mfma16h(kh0, aql0, z);                                                           \
      z = mfma16h(kh1, aql1, z);                                                           \
      z = mfma16h(kl0, aqh0, z);                                                           \
      z = mfma16h(kl1, aqh1, z);                                                           \
      (SD)[c] = z;                                                                         \
    } }

  #define SMAXPV(SC) {                                                                     \
    float rmax = (SC)[0][0];                                                               \
    _Pragma("unroll")                                                                      \
    for (int c = 0; c < 4; c++)                                                            \
      _Pragma("unroll")                                                                    \
      for (int i = 0; i < 4; i++) rmax = fmaxf(rmax, (SC)[c][i]);                          \
    rmax = fmaxf(rmax, __shfl_xor(rmax, 16));                                              \
    rmax = fmaxf(rmax, __shfl_xor(rmax, 32));                                              \
    if (__any(rmax - mI > 44.36f)){                                                        \
      const float mn = fmaxf(mI, rmax);                                                    \
      const float fac = exp2f((mI - mn)*EXPC);                                             \
      lI *= fac;                                                                           \
      mI = mn;                                                                             \
      _Pragma("unroll")                                                                    \
      for (int i = 0; i < 4; i++){                                                         \
        const float fi = __shfl(fac, g*4 + i);                                             \
        _Pragma("unroll")                                                                  \
        for (int dc = 0; dc < 4; dc++) acc[dc][i] *= fi;                                   \
      }                                                                                    \
    }                                                                                      \
    const float mC = mI*EXPC;                                                              \
    float rsum = 0.f;                                                                      \
    f16x8 aph[2], apl[2];                                                                  \
    _Pragma("unroll")                                                                      \
    for (int c = 0; c < 4; c++)                                                            \
      _Pragma("unroll")                                                                    \
      for (int i = 0; i < 4; i++){                                                         \
        const float p = exp2f(fmaf((SC)[c][i], EXPC, -mC));                                \
        const _Float16 ph = (_Float16)p;                                                   \
        aph[c>>1][(c&1)*4 + i] = ph;                                                       \
        apl[c>>1][(c&1)*4 + i] = (_Float16)(p - (float)ph);                                \
        rsum += p;                                                                         \
      }                                                                                    \
    rsum += __shfl_xor(rsum, 16);                                                          \
    rsum += __shfl_xor(rsum, 32);                                                          \
    lI += rsum;                                                                            \
    const _Float16* vt_h = pVc; const _Float16* vt_l = pVc + 4096;                         \
    _Pragma("unroll")                                                                      \
    for (int ks = 0; ks < 2; ks++){                                                        \
      _Pragma("unroll")                                                                    \
      for (int dc = 0; dc < 4; dc++){                                                      \
        const int vr = dc*16 + r16;                                                        \
        const f16x8 bvh = *(const f16x8*)&vt_h[vr*64 + ((ks*32 + g*8) ^ swk8)];            \
        const f16x8 bvl = *(const f16x8*)&vt_l[vr*64 + ((ks*32 + g*8) ^ swk8)];            \
        acc[dc] = mfma16h(aph[ks], bvh, acc[dc]);                                          \
        acc[dc] = mfma16h(apl[ks], bvh, acc[dc]);                                          \
        acc[dc] = mfma16h(aph[ks], bvl, acc[dc]);                                          \
      }                                                                                    \
    } }

  QKT(pKo, sA);                    // s for tile 0 (K0 staged+drained above)

  for (int tt = 0; tt < 8; tt++){
    { // even phase: t = 2*tt  (<= 14)
      const int t = 2*tt;
      if (t < 14) KSTAGE(pKs, t+2);
      VSTAGE(pVs, t+1);
      QKT(pKn, sB);
      SMAXPV(sA);
      __syncthreads();
      _Float16* tk = pKo; pKo = pKn; pKn = pKs; pKs = tk;
      _Float16* tv = pVc; pVc = pVs; pVs = tv;
    }
    { // odd phase: t = 2*tt+1 (<= 15)
      const int t = 2*tt+1;
      if (t < 14) KSTAGE(pKs, t+2);
      if (t < 15) VSTAGE(pVs, t+1);
      if (t < 15) QKT(pKn, sA);
      SMAXPV(sB);
      __syncthreads();
      _Float16* tk = pKo; pKo = pKn; pKn = pKs; pKs = tk;
      _Float16* tv = pVc; pVc = pVs; pVs = tv;
    }
  }
  #undef KSTAGE
  #undef VSTAGE
  #undef QKT
  #undef SMAXPV

  #pragma unroll
  for (int i = 0; i < 4; i++){
    const float li = __shfl(lI, g*4 + i);
    const float inv = 1.f/li;
    const int row = qt*64 + w*16 + g*4 + i;
    #pragma unroll
    for (int dc = 0; dc < 4; dc++){
      const size_t idx = (size_t)b*1048576 + (size_t)row*1024 + h*64 + dc*16 + r16;
      xout[idx] = acc[dc][i]*inv + xin[idx];
    }
  }
}

// ---------------- layernorm; SPLIT=1 writes fp16 hi/lo in swizzled A-layout ----------------
template<int SPLIT>
__global__ __launch_bounds__(256) void k_ln(const float* __restrict__ x, const float* __restrict__ gg,
                                            const float* __restrict__ bb, float* __restrict__ outf,
                                            _Float16* __restrict__ Oh, _Float16* __restrict__ Ol){
  const int row = blockIdx.x*4 + (threadIdx.x>>6);
  const int lane = threadIdx.x & 63;
  const float* xr = x + (size_t)row*1024;
  f32x4 v[4];
  float s = 0.f, q = 0.f;
  #pragma unroll
  for (int c = 0; c < 2; c++){
    v[c*2]   = *(const f32x4*)(xr + c*512 + lane*8);
    v[c*2+1] = *(const f32x4*)(xr + c*512 + lane*8 + 4);
    #pragma unroll
    for (int e = 0; e < 4; e++){
      s += v[c*2][e] + v[c*2+1][e];
      q += v[c*2][e]*v[c*2][e] + v[c*2+1][e]*v[c*2+1][e];
    }
  }
  for (int d = 1; d < 64; d <<= 1){ s += __shfl_xor(s,d); q += __shfl_xor(q,d); }
  const float mean = s * (1.f/1024.f);
  const float var  = q * (1.f/1024.f) - mean*mean;
  const float rstd = rsqrtf(var + 1e-5f);
  #pragma unroll
  for (int c = 0; c < 2; c++){
    const int col = c*512 + lane*8;
    f32x4 g0 = *(const f32x4*)(gg + col), g1 = *(const f32x4*)(gg + col + 4);
    f32x4 b0 = *(const f32x4*)(bb + col), b1 = *(const f32x4*)(bb + col + 4);
    float h[8];
    #pragma unroll
    for (int e = 0; e < 4; e++){
      h[e]   = (v[c*2][e]  -mean)*rstd*g0[e] + b0[e];
      h[e+4] = (v[c*2+1][e]-mean)*rstd*g1[e] + b1[e];
    }
    if (SPLIT){
      f16x8 Hv, Lv;
      #pragma unroll
      for (int e = 0; e < 8; e++){
        _Float16 hh = (_Float16)h[e];
        Hv[e] = hh; Lv[e] = (_Float16)(h[e] - (float)hh);
      }
      const size_t addr = (size_t)row*1024 + c*512 + (lane>>3)*64 + (((lane&7)*8) ^ ((row&7)*8));
      *(f16x8*)&Oh[addr] = Hv;
      *(f16x8*)&Ol[addr] = Lv;
    } else {
      f32x4 o0, o1;
      #pragma unroll
      for (int e = 0; e < 4; e++){ o0[e] = h[e]; o1[e] = h[e+4]; }
      *(f32x4*)(outf + (size_t)row*1024 + col) = o0;
      *(f32x4*)(outf + (size_t)row*1024 + col + 4) = o1;
    }
  }
}

// ---------------- bitlinear GEMM: C[2048,1024] = (Ah+Al).Wb^T * beta ----------------
// BM=BN=64, BK=64, 4 waves (2Mx2N, wave-tile 32x32), double-buffered gload staging.
// MODE 0: GELU -> split fp16 out (swizzled A-layout).
// MODE 1: += into fp32 residual; if Kh!=null, ALSO produce next layer's K/V split
//         layouts (fused presplit: this block == presplit unit t=by&15, bh=(by>>4)*16+bx).
template<int MODE>
__global__ __launch_bounds__(256) void k_gemm(const _Float16* __restrict__ Ah, const _Float16* __restrict__ Al,
                                              const _Float16* __restrict__ Wg,
                                              float* __restrict__ out32,
                                              _Float16* __restrict__ Oh, _Float16* __restrict__ Ol,
                                              const double* __restrict__ dabs_slot,
                                              _Float16* __restrict__ Kh, _Float16* __restrict__ Kl,
                                              _Float16* __restrict__ Vh, _Float16* __restrict__ Vl){
  __shared__ _Float16 smb[24576];   // 2 x (A-hi 4096 + A-lo 4096 + B 4096); reused post-loop
  const int tid = threadIdx.x, w = tid>>6, l = tid&63, g = l>>4, r16 = l&15;
  const int wm = w>>1, wn = w&1;
  const int n0 = blockIdx.x*64, m0 = blockIdx.y*64;
  const float scale = (float)(*dabs_slot * (1.0/1048576.0));
  const int swr = (r16&7)*8;
  f32x4 acc[2][2] = {};
  #define STAGE(buf, k0) { _Float16* Bp = smb + (buf)*12288;                              \
    _Pragma("unroll")                                                                     \
    for (int j = 0; j < 2; j++){                                                          \
      const int cb = (j*4 + w)*64; const int c = cb + l;                                  \
      const int r = c>>3; const int cc = (c&7)*8;                                         \
      gload_lds16(Ah + (size_t)(m0 + r)*1024 + (k0) + cc, Bp + cb*8);                     \
      gload_lds16(Al + (size_t)(m0 + r)*1024 + (k0) + cc, Bp + 4096 + cb*8);              \
      gload_lds16(Wg + (size_t)(n0 + r)*1024 + (k0) + cc, Bp + 8192 + cb*8);              \
    } }
  STAGE(0, 0);
  __syncthreads();
  for (int t = 0; t < 16; t++){
    if (t < 15) STAGE((t+1)&1, (t+1)*64);
    const _Float16* Bp = smb + (t&1)*12288;
    #pragma unroll
    for (int kk = 0; kk < 2; kk++){
      f16x8 ah[2], al[2], bf[2];
      const int col = (kk*32 + g*8) ^ swr;
      #pragma unroll
      for (int mi = 0; mi < 2; mi++){
        const int row = wm*32 + mi*16 + r16;
        ah[mi] = *(const f16x8*)&Bp[row*64 + col];
        al[mi] = *(const f16x8*)&Bp[4096 + row*64 + col];
      }
      #pragma unroll
      for (int ni = 0; ni < 2; ni++){
        const int row = wn*32 + ni*16 + r16;
        bf[ni] = *(const f16x8*)&Bp[8192 + row*64 + col];
      }
      #pragma unroll
      for (int mi = 0; mi < 2; mi++)
        #pragma unroll
        for (int ni = 0; ni < 2; ni++){
          acc[mi][ni] = mfma16h(ah[mi], bf[ni], acc[mi][ni]);
          acc[mi][ni] = mfma16h(al[mi], bf[ni], acc[mi][ni]);
        }
    }
    __syncthreads();
  }
  #undef STAGE
  // post-loop LDS reuse (all waves past final barrier): split-tile staging for fused KV
  _Float16* kh_t = smb;            // [64][72] token-major hi
  _Float16* kl_t = smb + 4608;     // [64][72] token-major lo
  _Float16* lhv  = smb + 9216;     // [64][72] d-major hi
  _Float16* llv  = smb + 13824;    // [64][72] d-major lo
  #pragma unroll
  for (int mi = 0; mi < 2; mi++)
    #pragma unroll
    for (int ni = 0; ni < 2; ni++)
      #pragma unroll
      for (int i = 0; i < 4; i++){
        const int rr = m0 + wm*32 + mi*16 + g*4 + i;
        const int cc = n0 + wn*32 + ni*16 + r16;
        float vv = acc[mi][ni][i] * scale;
        if (MODE == 0){
          vv = 0.5f*vv*(1.f + erff(vv*0.70710678118f));
          _Float16 hh = (_Float16)vv;
          const size_t addr = (size_t)rr*1024 + (cc & ~63) + ((cc & 63) ^ ((rr&7)*8));
          Oh[addr] = hh;
          Ol[addr] = (_Float16)(vv - (float)hh);
        } else {
          const size_t idx = (size_t)rr*1024 + cc;
          const float xnew = out32[idx] + vv;
          out32[idx] = xnew;
          if (Kh){
            const int nl = wm*32 + mi*16 + g*4 + i;   // token within tile
            const int dl = wn*32 + ni*16 + r16;       // d within head
            const _Float16 hh = (_Float16)xnew;
            const _Float16 lo = (_Float16)(xnew - (float)hh);
            kh_t[nl*72 + dl] = hh;  kl_t[nl*72 + dl] = lo;
            lhv [dl*72 + nl] = hh;  llv [dl*72 + nl] = lo;
          }
        }
      }
  if (MODE == 1 && Kh){
    __syncthreads();
    const int n = tid>>2, c0q = (tid&3)*16;
    const int bh = (blockIdx.y>>4)*16 + blockIdx.x;
    const int tseq = blockIdx.y & 15;
    const size_t kbase = ((size_t)bh*1024 + tseq*64 + n)*64;
    const int swn = PHI(n)*8;
    const size_t vbase = ((size_t)bh*64 + n)*1024 + tseq*64;
    const int sw2 = (n&7)*8;
    #pragma unroll
    for (int j = 0; j < 2; j++){
      const int db = c0q + j*8;
      *(f16x8*)&Kh[kbase + (db ^ swn)] = *(const f16x8*)&kh_t[n*72 + db];
      *(f16x8*)&Kl[kbase + (db ^ swn)] = *(const f16x8*)&kl_t[n*72 + db];
      *(f16x8*)&Vh[vbase + (db ^ sw2)] = *(const f16x8*)&lhv[n*72 + db];
      *(f16x8*)&Vl[vbase + (db ^ sw2)] = *(const f16x8*)&llv[n*72 + db];
    }
  }
}

extern "C" void kernel_launch(void* const* d_in, const int* in_sizes, int n_in,
                              void* d_out, int out_size, void* d_ws, size_t ws_size,
                              hipStream_t stream){
  const float* x_in = (const float*)d_in[0];
  const float* ln_g = (const float*)d_in[1];
  const float* ln_b = (const float*)d_in[2];
  const float* w1   = (const float*)d_in[3];
  const float* w2   = (const float*)d_in[4];
  const float* fg   = (const float*)d_in[5];
  const float* fb   = (const float*)d_in[6];

  char* ws = (char*)d_ws;
  double*   dsum  = (double*)ws;            // 12
  double*   dabs  = (double*)(ws + 96);     // 12
  _Float16* wb = (_Float16*)(ws + 256);     // 12 * 1M fp16 = 24 MB
  size_t o = 256 + 12ull*1048576ull*2ull;
  float* xA = (float*)(ws + o); o += 2048ull*1024*4;
  float* xB = (float*)(ws + o); o += 2048ull*1024*4;
  _Float16* Kh = (_Float16*)(ws + o); o += 2048ull*1024*2;
  _Float16* Kl = (_Float16*)(ws + o); o += 2048ull*1024*2;
  _Float16* Vh = (_Float16*)(ws + o); o += 2048ull*1024*2;
  _Float16* Vl = (_Float16*)(ws + o); o += 2048ull*1024*2;
  _Float16* Ahb = (_Float16*)(ws + o); o += 2048ull*1024*2;
  _Float16* Alb = (_Float16*)(ws + o); o += 2048ull*1024*2;
  _Float16* Ghb = (_Float16*)(ws + o); o += 2048ull*1024*2;
  _Float16* Glb = (_Float16*)(ws + o); o += 2048ull*1024*2;

  hipMemsetAsync(ws, 0, 256, stream);
  k_wstats  <<<dim3(32,12), 256, 0, stream>>>(w1, w2, dsum, dabs);
  k_binarize<<<6144,        256, 0, stream>>>(w1, w2, dsum, wb);
  k_presplit<<<dim3(16,32), 256, 0, stream>>>(x_in, Kh, Kl, Vh, Vl);

  const float* xc = x_in;
  for (int i = 0; i < 6; i++){
    float* xn = (i & 1) ? xB : xA;
    const bool last = (i == 5);
    k_attn    <<<dim3(32,16), 256, 0, stream>>>(Kh, Kl, Vh, Vl, xc, xn);
    k_ln<1>   <<<512, 256, 0, stream>>>(xn, ln_g + (size_t)i*1024, ln_b + (size_t)i*1024,
                                        nullptr, Ahb, Alb);
    k_gemm<0> <<<dim3(16,32), 256, 0, stream>>>(Ahb, Alb, wb + (size_t)i*1048576,
                                                nullptr, Ghb, Glb, &dabs[i],
                                                nullptr, nullptr, nullptr, nullptr);
    k_gemm<1> <<<dim3(16,32), 256, 0, stream>>>(Ghb, Glb, wb + (size_t)(6+i)*1048576,
                                                xn, nullptr, nullptr, &dabs[6+i],
                                                last ? nullptr : Kh, last ? nullptr : Kl,
                                                last ? nullptr : Vh, last ? nullptr : Vl);
    xc = xn;
  }
  k_ln<0><<<512, 256, 0, stream>>>(xc, fg, fb, (float*)d_out, nullptr, nullptr);
}